// Round 11
// baseline (139.163 us; speedup 1.0000x reference)
//
#include <hip/hip_runtime.h>
#include <hip/hip_bf16.h>

typedef __attribute__((ext_vector_type(8))) short bf16x8;
typedef __attribute__((ext_vector_type(4))) float f32x4;

#define BATCH 32
#define SEQ   2048
#define PSTR  20    // fallback kernel only
#define KSTR  72    // fallback kernel only
#define VSTR  36    // fallback + prepkv staging
#define LOG2E 1.44269504088896340736f
#define QSCALE (0.125f * LOG2E)
#define NEGL  (-1000000.0f * LOG2E)
#define NITEMS (BATCH * 32)

__device__ __forceinline__ unsigned int pk2(float lo, float hi) {
    __hip_bfloat162 h2 = __float22bfloat162_rn(make_float2(lo, hi));  // v_cvt_pk_bf16_f32
    return *reinterpret_cast<unsigned int*>(&h2);
}

__device__ __forceinline__ void dma16(const short* g, short* l) {
    __builtin_amdgcn_global_load_lds((const __attribute__((address_space(1))) void*)g,
                                     (__attribute__((address_space(3))) void*)l, 16, 0, 0);
}

// P-exchange slot: kp bits 0<->2 swapped, x16, +q -> 2-way banks both sides.
__device__ __forceinline__ int pslot(int kp, int q) {
    const int kp2 = (kp & 0x1A) | ((kp & 1) << 2) | ((kp >> 2) & 1);
    return (kp2 << 4) + q;
}

// standalone prep (fallback path only)
__global__ void prep_vl(const int* __restrict__ VL, int* __restrict__ meta) {
    __shared__ int sv[BATCH];
    const int t = threadIdx.x;
    int odd = (t < 16) ? VL[2 * t + 1] : 0;
    const bool is64 = (__ballot(odd != 0) == 0ULL);
    if (t < BATCH) {
        int x = is64 ? VL[2 * t] : VL[t];
        x = x < 0 ? 0 : (x > SEQ ? SEQ : x);
        sv[t] = x;
    }
    __syncthreads();
    if (t < BATCH) {
        const int x = sv[t];
        int rank = 0;
        for (int j = 0; j < BATCH; ++j) {
            const int y = sv[j];
            rank += (y > x) || (y == x && j < t);
        }
        meta[rank] = x;
        meta[BATCH + rank] = t;
    }
}

// K fp32->bf16 row-major; V fp32->bf16 transposed [B][D][S]; block BATCH*32
// does the meta rank-sort wave-synchronously AND zeroes the work-queue counter.
__global__ __launch_bounds__(256) void prepkv(const float* __restrict__ Kp,
                                              const float* __restrict__ Vp,
                                              const int* __restrict__ VL,
                                              short* __restrict__ Kb,
                                              short* __restrict__ Vt,
                                              int* __restrict__ meta,
                                              int* __restrict__ cnt) {
    __shared__ unsigned int l[64 * VSTR];
    __shared__ int sv[BATCH];
    const int tid = threadIdx.x;
    if (blockIdx.x == BATCH * 32) {
        if (tid == 0) *cnt = 0;               // queue reset every launch (ws re-poisoned)
        if (tid < 64) {
            int odd = (tid < 16) ? VL[2 * tid + 1] : 0;
            const bool is64 = (__ballot(odd != 0) == 0ULL);   // lens>=1
            if (tid < BATCH) {
                int x = is64 ? VL[2 * tid] : VL[tid];
                x = x < 0 ? 0 : (x > SEQ ? SEQ : x);
                sv[tid] = x;
            }
            asm volatile("s_waitcnt lgkmcnt(0)" ::: "memory");
            if (tid < BATCH) {
                const int x = sv[tid];
                int rank = 0;
                for (int j = 0; j < BATCH; ++j) {
                    const int y = sv[j];
                    rank += (y > x) || (y == x && j < tid);
                }
                meta[rank] = x;
                meta[BATCH + rank] = tid;
            }
        }
        return;
    }
    const int b = blockIdx.x >> 5, kt = blockIdx.x & 31, kb = kt * 64;
    const float* Kv = Kp + ((size_t)b * SEQ + kb) * 64;
    const float* Vb = Vp + ((size_t)b * SEQ + kb) * 64;
    #pragma unroll
    for (int h = 0; h < 4; ++h) {
        const int c = tid + h * 256;
        const int row = c >> 4, col = (c & 15) * 4;
        f32x4 x = *(const f32x4*)(Kv + row * 64 + col);
        unsigned int* dst = (unsigned int*)(Kb + ((size_t)b * SEQ + kb + row) * 64 + col);
        dst[0] = pk2(x[0], x[1]); dst[1] = pk2(x[2], x[3]);
    }
    #pragma unroll
    for (int h = 0; h < 2; ++h) {
        const int u = tid + h * 256;
        const int d4 = (u & 3) + ((u >> 7) << 2);
        const int kp = (u >> 2) & 31;
        f32x4 a = *(const f32x4*)(Vb + (2 * kp) * 64 + d4 * 4);
        f32x4 c = *(const f32x4*)(Vb + (2 * kp + 1) * 64 + d4 * 4);
        #pragma unroll
        for (int j = 0; j < 4; ++j)
            l[(d4 * 4 + j) * VSTR + kp] = pk2(a[j], c[j]);
    }
    __syncthreads();
    const int d = tid >> 2, cg = tid & 3;
    unsigned int w[8];
    #pragma unroll
    for (int j = 0; j < 8; ++j) w[j] = l[d * VSTR + cg * 8 + j];
    unsigned int* dst = (unsigned int*)(Vt + (size_t)(b * 64 + d) * SEQ + kb + cg * 16);
    #pragma unroll
    for (int j = 0; j < 8; ++j) dst[j] = w[j];
}

// ---- main: persistent blocks + dynamic LPT work queue. Items sorted by vl
// desc (slot rank). 768 blocks (3/CU) stay resident; finished blocks backfill
// from the queue -> occupancy holds flat instead of decaying 16->4 waves/CU.
__global__ __launch_bounds__(256, 3)
void attn_fwd(const float* __restrict__ Qp, const short* __restrict__ Kb,
              const short* __restrict__ Vt, const int* __restrict__ meta,
              int* __restrict__ cnt, float* __restrict__ Out) {
    constexpr int S = SEQ;
    __shared__ short bK2[2 * 64 * 64];
    __shared__ short bV2[2 * 64 * 64];
    __shared__ unsigned int lPt[4 * 512];
    __shared__ int s_item;

    const int tid  = threadIdx.x;
    const int wave = tid >> 6, lane = tid & 63;
    const int l15  = lane & 15, grp = lane >> 4;
    const int r7   = l15 & 7;
    const int r8 = lane >> 3, s8 = lane & 7, csw = s8 ^ r8;
    short* lK0 = &bK2[wave * 16 * 64];
    short* lV0 = &bV2[wave * 16 * 64];
    unsigned int* pw = &lPt[wave * 512];

    for (;;) {
        if (tid == 0) s_item = atomicAdd(cnt, 1);
        __syncthreads();   // broadcast item + fence: prev item's LDS reads all done
        const int item = s_item;
        if (item >= NITEMS) return;
        const int slot = item >> 5, qt = item & 31;   // slot asc = vl desc = LPT order

        const int vl = meta[slot], batch = meta[BATCH + slot];
        const int ntiles = (vl + 63) >> 6;

        const short* Kbb = Kb + (size_t)batch * S * 64;
        const short* Vtb = Vt + (size_t)batch * 64 * S;
        const short* gK0 = Kbb + (wave * 16 + r8) * 64 + csw * 8;
        const short* gV0 = Vtb + (size_t)(wave * 16 + r8) * S + csw * 8;

        if (ntiles > 0) {                     // tile-0 DMA first: overlaps Q load below
            dma16(gK0,                 lK0);
            dma16(gK0 + 8 * 64,        lK0 + 8 * 64);
            dma16(gV0,                 lV0);
            dma16(gV0 + (size_t)8 * S, lV0 + 8 * 64);
        }

        // Q B-fragment, scale folded (scores exit MFMA in log2 domain)
        bf16x8 qf[2];
        {
            const float* qb = Qp + ((size_t)batch * S + qt * 64 + wave * 16 + l15) * 64 + grp * 8;
            #pragma unroll
            for (int kf = 0; kf < 2; ++kf) {
                f32x4 a = *(const f32x4*)(qb + kf * 32);
                f32x4 c = *(const f32x4*)(qb + kf * 32 + 4);
                union { bf16x8 v; unsigned int u[4]; } qq;
                qq.u[0] = pk2(a[0] * QSCALE, a[1] * QSCALE);
                qq.u[1] = pk2(a[2] * QSCALE, a[3] * QSCALE);
                qq.u[2] = pk2(c[0] * QSCALE, c[1] * QSCALE);
                qq.u[3] = pk2(c[2] * QSCALE, c[3] * QSCALE);
                qf[kf] = qq.v;
            }
        }

        f32x4 o[4] = {{0.f,0.f,0.f,0.f},{0.f,0.f,0.f,0.f},{0.f,0.f,0.f,0.f},{0.f,0.f,0.f,0.f}};
        float lpart = 0.f;

        for (int kt = 0; kt < ntiles; ++kt) {
            __syncthreads();   // drains tile kt's DMA (vmcnt) + aligns waves
            if (kt + 1 < ntiles) {
                const int nb  = ((kt + 1) & 1) * 4096;
                const int kbn = (kt + 1) * 64;
                dma16(gK0 + kbn * 64,            lK0 + nb);
                dma16(gK0 + kbn * 64 + 8 * 64,   lK0 + nb + 8 * 64);
                dma16(gV0 + kbn,                 lV0 + nb);
                dma16(gV0 + kbn + (size_t)8 * S, lV0 + nb + 8 * 64);
            }
            const short* bK = &bK2[(kt & 1) * 4096];
            const short* bV = &bV2[(kt & 1) * 4096];

            // S^T = K Qs^T : col=q=l15, row=key=ct*16+grp*4+r (log2 domain)
            f32x4 st[4] = {{0.f,0.f,0.f,0.f},{0.f,0.f,0.f,0.f},{0.f,0.f,0.f,0.f},{0.f,0.f,0.f,0.f}};
            #pragma unroll
            for (int kf = 0; kf < 2; ++kf) {
                #pragma unroll
                for (int ct = 0; ct < 4; ++ct) {
                    bf16x8 kfr = *(const bf16x8*)&bK[((ct * 16 + l15) << 6) +
                                                     (((kf * 4 + grp) ^ r7) << 3)];
                    st[ct] = __builtin_amdgcn_mfma_f32_16x16x32_bf16(kfr, qf[kf], st[ct], 0, 0, 0);
                }
            }

            // mask only the last PARTIAL tile (wave-uniform branch)
            if (kt == ntiles - 1 && (vl & 63) != 0) {
                const int kbase = kt * 64;
                #pragma unroll
                for (int ct = 0; ct < 4; ++ct)
                    #pragma unroll
                    for (int r = 0; r < 4; ++r) {
                        const bool valid = (kbase + ct * 16 + grp * 4 + r) < vl;
                        st[ct][r] = valid ? st[ct][r] : NEGL;
                    }
            }

            // p = exp2(s') with NO max subtraction (shift-invariant, bounded
            // scores; masked -> exp2(-1.4e6) == 0 exactly)
            #pragma unroll
            for (int ct = 0; ct < 4; ++ct) {
                #pragma unroll
                for (int r = 0; r < 4; ++r) {
                    st[ct][r] = exp2f(st[ct][r]);
                    lpart += st[ct][r];
                }
                #pragma unroll
                for (int a = 0; a < 2; ++a)
                    pw[pslot(ct * 8 + grp * 2 + a, l15)] = pk2(st[ct][2 * a], st[ct][2 * a + 1]);
            }
            asm volatile("s_waitcnt lgkmcnt(0)" ::: "memory");  // wave-private P^T

            // O^T += V^T P^T
            #pragma unroll
            for (int kk = 0; kk < 2; ++kk) {
                union { bf16x8 v; unsigned int u[4]; } pf;
                #pragma unroll
                for (int jj = 0; jj < 4; ++jj)
                    pf.u[jj] = pw[pslot(kk * 16 + grp * 4 + jj, l15)];
                #pragma unroll
                for (int dt = 0; dt < 4; ++dt) {
                    bf16x8 vf = *(const bf16x8*)&bV[((dt * 16 + l15) << 6) +
                                                    (((kk * 4 + grp) ^ r7) << 3)];
                    o[dt] = __builtin_amdgcn_mfma_f32_16x16x32_bf16(vf, pf.v, o[dt], 0, 0, 0);
                }
            }
        }

        float lrun = lpart;
        lrun += __shfl_xor(lrun, 16);
        lrun += __shfl_xor(lrun, 32);

        const float inv = (lrun > 0.f) ? 1.0f / lrun : 0.f;
        const size_t orow = ((size_t)batch * S + qt * 64 + wave * 16 + l15) * 64;
        #pragma unroll
        for (int dt = 0; dt < 4; ++dt) {
            f32x4 w = o[dt];
            w[0] *= inv; w[1] *= inv; w[2] *= inv; w[3] *= inv;
            *(f32x4*)(Out + orow + dt * 16 + grp * 4) = w;
        }
    }
}

// ---------------- fallback (used only if ws too small) ----------------
__device__ __forceinline__ void load_tile_fb(const float* __restrict__ Kb,
                                             const float* __restrict__ Vb,
                                             int tid, f32x4 kv[4], f32x4 vv[4]) {
    #pragma unroll
    for (int h = 0; h < 4; ++h) {
        const int c = tid + h * 256;
        kv[h] = *(const f32x4*)(Kb + (c >> 4) * 64 + (c & 15) * 4);
    }
    #pragma unroll
    for (int h = 0; h < 2; ++h) {
        const int u  = tid + h * 256;
        const int d4 = (u & 3) + ((u >> 7) << 2);
        const int kp = (u >> 2) & 31;
        vv[2 * h]     = *(const f32x4*)(Vb + (2 * kp) * 64 + d4 * 4);
        vv[2 * h + 1] = *(const f32x4*)(Vb + (2 * kp + 1) * 64 + d4 * 4);
    }
}

__global__ __launch_bounds__(256, 4)
void attn_fb(const float* __restrict__ Qp, const float* __restrict__ Kp,
             const float* __restrict__ Vp, const int* __restrict__ meta,
             float* __restrict__ Out) {
    constexpr int S = SEQ;
    constexpr int qtiles = S >> 6;
    __shared__ short        lK [64 * KSTR];
    __shared__ unsigned int lVt[64 * VSTR];
    __shared__ unsigned int lPt[4 * 32 * PSTR];
    const int tid = threadIdx.x;
    const int wave = tid >> 6, lane = tid & 63;
    const int l15 = lane & 15, grp = lane >> 4;
    const int slot = blockIdx.x / qtiles, qt = blockIdx.x % qtiles;
    const int vl = meta[slot], batch = meta[BATCH + slot];
    const int ntiles = (vl + 63) >> 6;
    const float* Kb = Kp + (size_t)batch * S * 64;
    const float* Vb = Vp + (size_t)batch * S * 64;
    bf16x8 qf[2];
    {
        const float* qb = Qp + ((size_t)batch * S + qt * 64 + wave * 16 + l15) * 64 + grp * 8;
        #pragma unroll
        for (int kf = 0; kf < 2; ++kf) {
            f32x4 a = *(const f32x4*)(qb + kf * 32);
            f32x4 b = *(const f32x4*)(qb + kf * 32 + 4);
            union { bf16x8 v; unsigned int u[4]; } qq;
            qq.u[0] = pk2(a[0], a[1]); qq.u[1] = pk2(a[2], a[3]);
            qq.u[2] = pk2(b[0], b[1]); qq.u[3] = pk2(b[2], b[3]);
            qf[kf] = qq.v;
        }
    }
    f32x4 o[4] = {{0.f,0.f,0.f,0.f},{0.f,0.f,0.f,0.f},{0.f,0.f,0.f,0.f},{0.f,0.f,0.f,0.f}};
    float mrun = -INFINITY, lrun = 0.f;
    unsigned int* pw = &lPt[wave * 32 * PSTR];
    f32x4 kv[4], vv[4];
    if (ntiles > 0) load_tile_fb(Kb, Vb, tid, kv, vv);
    for (int kt = 0; kt < ntiles; ++kt) {
        const int kb = kt * 64;
        __syncthreads();
        #pragma unroll
        for (int h = 0; h < 4; ++h) {
            const int c = tid + h * 256;
            const int row = c >> 4, col = (c & 15) * 4;
            union { f32x4 f; float e[4]; } x; x.f = kv[h];
            unsigned int* dst = (unsigned int*)&lK[row * KSTR + col];
            dst[0] = pk2(x.e[0], x.e[1]); dst[1] = pk2(x.e[2], x.e[3]);
        }
        #pragma unroll
        for (int h = 0; h < 2; ++h) {
            const int u  = tid + h * 256;
            const int d4 = (u & 3) + ((u >> 7) << 2);
            const int kp = (u >> 2) & 31;
            union { f32x4 f; float e[4]; } a, b;
            a.f = vv[2 * h]; b.f = vv[2 * h + 1];
            #pragma unroll
            for (int j = 0; j < 4; ++j)
                lVt[(d4 * 4 + j) * VSTR + kp] = pk2(a.e[j], b.e[j]);
        }
        if (kt + 1 < ntiles) load_tile_fb(Kb + (size_t)(kb + 64) * 64, Vb + (size_t)(kb + 64) * 64, tid, kv, vv);
        __syncthreads();
        f32x4 st[4] = {{0.f,0.f,0.f,0.f},{0.f,0.f,0.f,0.f},{0.f,0.f,0.f,0.f},{0.f,0.f,0.f,0.f}};
        #pragma unroll
        for (int kf = 0; kf < 2; ++kf) {
            #pragma unroll
            for (int ct = 0; ct < 4; ++ct) {
                bf16x8 kfr = *(const bf16x8*)&lK[(ct * 16 + l15) * KSTR + kf * 32 + grp * 8];
                st[ct] = __builtin_amdgcn_mfma_f32_16x16x32_bf16(kfr, qf[kf], st[ct], 0, 0, 0);
            }
        }
        #pragma unroll
        for (int ct = 0; ct < 4; ++ct)
            #pragma unroll
            for (int r = 0; r < 4; ++r) {
                const bool valid = (kb + ct * 16 + grp * 4 + r) < vl;
                st[ct][r] = valid ? st[ct][r] * (0.125f * LOG2E) : NEGL;
            }
        float t0 = fmaxf(fmaxf(st[0][0], st[0][1]), fmaxf(st[0][2], st[0][3]));
        float t1 = fmaxf(fmaxf(st[1][0], st[1][1]), fmaxf(st[1][2], st[1][3]));
        float t2 = fmaxf(fmaxf(st[2][0], st[2][1]), fmaxf(st[2][2], st[2][3]));
        float t3 = fmaxf(fmaxf(st[3][0], st[3][1]), fmaxf(st[3][2], st[3][3]));
        float tm = fmaxf(fmaxf(t0, t1), fmaxf(t2, t3));
        tm = fmaxf(tm, __shfl_xor(tm, 16));
        tm = fmaxf(tm, __shfl_xor(tm, 32));
        const float mnew  = fmaxf(mrun, tm);
        const float alpha = exp2f(mrun - mnew);
        mrun = mnew;
        lrun *= alpha;
        #pragma unroll
        for (int dt = 0; dt < 4; ++dt)
            #pragma unroll
            for (int r = 0; r < 4; ++r) o[dt][r] *= alpha;
        float rs = 0.f;
        #pragma unroll
        for (int ct = 0; ct < 4; ++ct) {
            #pragma unroll
            for (int r = 0; r < 4; ++r) {
                st[ct][r] = exp2f(st[ct][r] - mrun);
                rs += st[ct][r];
            }
            #pragma unroll
            for (int a = 0; a < 2; ++a)
                pw[(ct * 8 + grp * 2 + a) * PSTR + l15] = pk2(st[ct][2 * a], st[ct][2 * a + 1]);
        }
        rs += __shfl_xor(rs, 16);
        rs += __shfl_xor(rs, 32);
        lrun += rs;
        asm volatile("s_waitcnt lgkmcnt(0)" ::: "memory");
        #pragma unroll
        for (int kk = 0; kk < 2; ++kk) {
            union { bf16x8 v; unsigned int u[4]; } pf;
            #pragma unroll
            for (int jj = 0; jj < 4; ++jj)
                pf.u[jj] = pw[(kk * 16 + grp * 4 + jj) * PSTR + l15];
            #pragma unroll
            for (int dt = 0; dt < 4; ++dt) {
                bf16x8 vf = *(const bf16x8*)&lVt[(dt * 16 + l15) * VSTR + kk * 16 + grp * 4];
                o[dt] = __builtin_amdgcn_mfma_f32_16x16x32_bf16(vf, pf.v, o[dt], 0, 0, 0);
            }
        }
    }
    const float inv = (lrun > 0.f) ? 1.0f / lrun : 0.f;
    const size_t orow = ((size_t)batch * S + qt * 64 + wave * 16 + l15) * 64;
    #pragma unroll
    for (int dt = 0; dt < 4; ++dt) {
        f32x4 w = o[dt];
        w[0] *= inv; w[1] *= inv; w[2] *= inv; w[3] *= inv;
        *(f32x4*)(Out + orow + dt * 16 + grp * 4) = w;
    }
}

extern "C" void kernel_launch(void* const* d_in, const int* in_sizes, int n_in,
                              void* d_out, int out_size, void* d_ws, size_t ws_size,
                              hipStream_t stream) {
    const float* Q  = (const float*)d_in[0];
    const float* K  = (const float*)d_in[1];
    const float* V  = (const float*)d_in[2];
    const int*   VL = (const int*)d_in[3];
    int* meta = (int*)d_ws;                    // 64 ints
    int* cnt  = (int*)d_ws + 64;               // queue counter
    const size_t need = 512 + 2 * (size_t)BATCH * SEQ * 64 * sizeof(short);  // ~16.8 MB
    dim3 block(256);
    if (ws_size >= need) {
        short* Kb = (short*)((char*)d_ws + 512);
        short* Vt = Kb + (size_t)BATCH * SEQ * 64;
        prepkv<<<dim3(BATCH * 32 + 1), block, 0, stream>>>(K, V, VL, Kb, Vt, meta, cnt);
        attn_fwd<<<dim3(768), block, 0, stream>>>(Q, Kb, Vt, meta, cnt, (float*)d_out);
    } else {
        prep_vl<<<1, 64, 0, stream>>>(VL, meta);
        attn_fb<<<dim3(BATCH * (SEQ >> 6)), block, 0, stream>>>(Q, K, V, meta, (float*)d_out);
    }
}

// Round 12
// 131.683 us; speedup vs baseline: 1.0568x; 1.0568x over previous
//
#include <hip/hip_runtime.h>
#include <hip/hip_bf16.h>

typedef __attribute__((ext_vector_type(8))) short bf16x8;
typedef __attribute__((ext_vector_type(4))) float f32x4;

#define BATCH 32
#define SEQ   2048
#define PSTR  20    // fallback kernel only
#define KSTR  72    // fallback kernel only
#define VSTR  36    // fallback + prepkv staging
#define LOG2E 1.44269504088896340736f
#define QSCALE (0.125f * LOG2E)
#define NEGL  (-1000000.0f * LOG2E)

__device__ __forceinline__ unsigned int pk2(float lo, float hi) {
    __hip_bfloat162 h2 = __float22bfloat162_rn(make_float2(lo, hi));  // v_cvt_pk_bf16_f32
    return *reinterpret_cast<unsigned int*>(&h2);
}

__device__ __forceinline__ void dma16(const short* g, short* l) {
    __builtin_amdgcn_global_load_lds((const __attribute__((address_space(1))) void*)g,
                                     (__attribute__((address_space(3))) void*)l, 16, 0, 0);
}

// P-exchange slot: kp bits 0<->2 swapped, x16, +q -> 2-way banks both sides.
__device__ __forceinline__ int pslot(int kp, int q) {
    const int kp2 = (kp & 0x1A) | ((kp & 1) << 2) | ((kp >> 2) & 1);
    return (kp2 << 4) + q;
}

// standalone prep (fallback path only)
__global__ void prep_vl(const int* __restrict__ VL, int* __restrict__ meta) {
    __shared__ int sv[BATCH];
    const int t = threadIdx.x;
    int odd = (t < 16) ? VL[2 * t + 1] : 0;
    const bool is64 = (__ballot(odd != 0) == 0ULL);
    if (t < BATCH) {
        int x = is64 ? VL[2 * t] : VL[t];
        x = x < 0 ? 0 : (x > SEQ ? SEQ : x);
        sv[t] = x;
    }
    __syncthreads();
    if (t < BATCH) {
        const int x = sv[t];
        int rank = 0;
        for (int j = 0; j < BATCH; ++j) {
            const int y = sv[j];
            rank += (y > x) || (y == x && j < t);
        }
        meta[rank] = x;
        meta[BATCH + rank] = t;
    }
}

// K fp32->bf16 row-major [b][key][d]; V fp32->bf16 TILE-MAJOR transposed
// Vt[b][kt][d][64 keys] (packed key-pairs) so each block writes one contiguous
// 8 KB extent (round-11 post-mortem: the old [b][d][SEQ] layout scattered
// 128 B segments at 4 KB stride -> 2x ideal prepkv time). Block BATCH*32 does
// the meta rank-sort wave-synchronously.
__global__ __launch_bounds__(256) void prepkv(const float* __restrict__ Kp,
                                              const float* __restrict__ Vp,
                                              const int* __restrict__ VL,
                                              short* __restrict__ Kb,
                                              short* __restrict__ Vt,
                                              int* __restrict__ meta) {
    __shared__ unsigned int l[64 * VSTR];
    __shared__ int sv[BATCH];
    const int tid = threadIdx.x;
    if (blockIdx.x == BATCH * 32) {
        if (tid < 64) {
            int odd = (tid < 16) ? VL[2 * tid + 1] : 0;
            const bool is64 = (__ballot(odd != 0) == 0ULL);   // lens>=1
            if (tid < BATCH) {
                int x = is64 ? VL[2 * tid] : VL[tid];
                x = x < 0 ? 0 : (x > SEQ ? SEQ : x);
                sv[tid] = x;
            }
            asm volatile("s_waitcnt lgkmcnt(0)" ::: "memory");
            if (tid < BATCH) {
                const int x = sv[tid];
                int rank = 0;
                for (int j = 0; j < BATCH; ++j) {
                    const int y = sv[j];
                    rank += (y > x) || (y == x && j < tid);
                }
                meta[rank] = x;
                meta[BATCH + rank] = tid;
            }
        }
        return;
    }
    const int b = blockIdx.x >> 5, kt = blockIdx.x & 31, kb = kt * 64;
    const float* Kv = Kp + ((size_t)b * SEQ + kb) * 64;
    const float* Vb = Vp + ((size_t)b * SEQ + kb) * 64;
    #pragma unroll
    for (int h = 0; h < 4; ++h) {
        const int c = tid + h * 256;
        const int row = c >> 4, col = (c & 15) * 4;
        f32x4 x = *(const f32x4*)(Kv + row * 64 + col);
        unsigned int* dst = (unsigned int*)(Kb + ((size_t)b * SEQ + kb + row) * 64 + col);
        dst[0] = pk2(x[0], x[1]); dst[1] = pk2(x[2], x[3]);
    }
    #pragma unroll
    for (int h = 0; h < 2; ++h) {
        const int u = tid + h * 256;
        const int d4 = (u & 3) + ((u >> 7) << 2);
        const int kp = (u >> 2) & 31;
        f32x4 a = *(const f32x4*)(Vb + (2 * kp) * 64 + d4 * 4);
        f32x4 c = *(const f32x4*)(Vb + (2 * kp + 1) * 64 + d4 * 4);
        #pragma unroll
        for (int j = 0; j < 4; ++j)
            l[(d4 * 4 + j) * VSTR + kp] = pk2(a[j], c[j]);
    }
    __syncthreads();
    // tile-major write: uint index ((b*32+kt)*64 + d)*32 + kp -> contiguous 8 KB/block
    const int d = tid >> 2, cg = tid & 3;
    unsigned int w[8];
    #pragma unroll
    for (int j = 0; j < 8; ++j) w[j] = l[d * VSTR + cg * 8 + j];
    unsigned int* dst = (unsigned int*)Vt + ((size_t)(b * 32 + kt) * 64 + d) * 32 + cg * 8;
    #pragma unroll
    for (int j = 0; j < 8; ++j) dst[j] = w[j];
}

// ---- main (round-10 structure: 1024 blocks, snake LPT, DMA double-buffer,
// no online softmax). Round-11's persistent queue REGRESSED (58 vs 50.5 us):
// 1.33 items/block gave no backfill, 3/CU < 4/CU parallelism. Reverted. ----
__global__ __launch_bounds__(256, 4)
void attn_fwd(const float* __restrict__ Qp, const short* __restrict__ Kb,
              const short* __restrict__ Vt, const int* __restrict__ meta,
              float* __restrict__ Out) {
    constexpr int S = SEQ;
    __shared__ short bK2[2 * 64 * 64];
    __shared__ short bV2[2 * 64 * 64];
    __shared__ unsigned int lPt[4 * 512];

    const int tid  = threadIdx.x;
    const int wave = tid >> 6, lane = tid & 63;
    const int l15  = lane & 15, grp = lane >> 4;
    const int r7   = l15 & 7;

    // snake remap: CU c gets slots {k,15-k,16+k,31-k} -> balanced tile sums
    const int g  = blockIdx.x >> 8;
    const int k8 = (blockIdx.x >> 5) & 7;
    const int qt = blockIdx.x & 31;
    const int slot = (g << 3) + ((g & 1) ? 7 - k8 : k8);

    const int vl = meta[slot], batch = meta[BATCH + slot];
    const int ntiles = (vl + 63) >> 6;

    const short* Kbb = Kb + (size_t)batch * S * 64;
    const short* Vtb = Vt + (size_t)batch * 32 * 4096;   // tile-major: 4096 shorts per tile

    const int r8 = lane >> 3, s8 = lane & 7, csw = s8 ^ r8;
    const short* gK0 = Kbb + (wave * 16 + r8) * 64 + csw * 8;
    const short* gV0 = Vtb + (wave * 16 + r8) * 64 + csw * 8;
    short* lK0 = &bK2[wave * 16 * 64];
    short* lV0 = &bV2[wave * 16 * 64];

    // Q B-fragment, scale folded (scores exit MFMA in log2 domain)
    bf16x8 qf[2];
    {
        const float* qb = Qp + ((size_t)batch * S + qt * 64 + wave * 16 + l15) * 64 + grp * 8;
        #pragma unroll
        for (int kf = 0; kf < 2; ++kf) {
            f32x4 a = *(const f32x4*)(qb + kf * 32);
            f32x4 c = *(const f32x4*)(qb + kf * 32 + 4);
            union { bf16x8 v; unsigned int u[4]; } qq;
            qq.u[0] = pk2(a[0] * QSCALE, a[1] * QSCALE);
            qq.u[1] = pk2(a[2] * QSCALE, a[3] * QSCALE);
            qq.u[2] = pk2(c[0] * QSCALE, c[1] * QSCALE);
            qq.u[3] = pk2(c[2] * QSCALE, c[3] * QSCALE);
            qf[kf] = qq.v;
        }
    }

    f32x4 o[4] = {{0.f,0.f,0.f,0.f},{0.f,0.f,0.f,0.f},{0.f,0.f,0.f,0.f},{0.f,0.f,0.f,0.f}};
    float lpart = 0.f;                      // per-lane partial Σp; reduced ONCE at end
    unsigned int* pw = &lPt[wave * 512];

    if (ntiles > 0) {
        dma16(gK0,          lK0);
        dma16(gK0 + 8 * 64, lK0 + 8 * 64);
        dma16(gV0,          lV0);
        dma16(gV0 + 8 * 64, lV0 + 8 * 64);
    }

    for (int kt = 0; kt < ntiles; ++kt) {
        __syncthreads();
        if (kt + 1 < ntiles) {
            const int nb = ((kt + 1) & 1) * 4096;
            const int ko = (kt + 1) * 4096;       // shorts per 64x64 tile
            dma16(gK0 + ko,          lK0 + nb);
            dma16(gK0 + ko + 8 * 64, lK0 + nb + 8 * 64);
            dma16(gV0 + ko,          lV0 + nb);
            dma16(gV0 + ko + 8 * 64, lV0 + nb + 8 * 64);
        }
        const short* bK = &bK2[(kt & 1) * 4096];
        const short* bV = &bV2[(kt & 1) * 4096];

        // S^T = K Qs^T : col=q=l15, row=key=ct*16+grp*4+r (log2 domain)
        f32x4 st[4] = {{0.f,0.f,0.f,0.f},{0.f,0.f,0.f,0.f},{0.f,0.f,0.f,0.f},{0.f,0.f,0.f,0.f}};
        #pragma unroll
        for (int kf = 0; kf < 2; ++kf) {
            #pragma unroll
            for (int ct = 0; ct < 4; ++ct) {
                bf16x8 kfr = *(const bf16x8*)&bK[((ct * 16 + l15) << 6) +
                                                 (((kf * 4 + grp) ^ r7) << 3)];
                st[ct] = __builtin_amdgcn_mfma_f32_16x16x32_bf16(kfr, qf[kf], st[ct], 0, 0, 0);
            }
        }

        // mask only the last PARTIAL tile (wave-uniform branch)
        if (kt == ntiles - 1 && (vl & 63) != 0) {
            const int kbase = kt * 64;
            #pragma unroll
            for (int ct = 0; ct < 4; ++ct)
                #pragma unroll
                for (int r = 0; r < 4; ++r) {
                    const bool valid = (kbase + ct * 16 + grp * 4 + r) < vl;
                    st[ct][r] = valid ? st[ct][r] : NEGL;
                }
        }

        // p = exp2(s') with NO max subtraction (shift-invariant, scores bounded;
        // masked -> exp2(-1.4e6) == 0 exactly)
        #pragma unroll
        for (int ct = 0; ct < 4; ++ct) {
            #pragma unroll
            for (int r = 0; r < 4; ++r) {
                st[ct][r] = exp2f(st[ct][r]);
                lpart += st[ct][r];
            }
            #pragma unroll
            for (int a = 0; a < 2; ++a)
                pw[pslot(ct * 8 + grp * 2 + a, l15)] = pk2(st[ct][2 * a], st[ct][2 * a + 1]);
        }
        asm volatile("s_waitcnt lgkmcnt(0)" ::: "memory");  // wave-private P^T visibility

        // O^T += V^T P^T
        #pragma unroll
        for (int kk = 0; kk < 2; ++kk) {
            union { bf16x8 v; unsigned int u[4]; } pf;
            #pragma unroll
            for (int jj = 0; jj < 4; ++jj)
                pf.u[jj] = pw[pslot(kk * 16 + grp * 4 + jj, l15)];
            #pragma unroll
            for (int dt = 0; dt < 4; ++dt) {
                bf16x8 vf = *(const bf16x8*)&bV[((dt * 16 + l15) << 6) +
                                                (((kk * 4 + grp) ^ r7) << 3)];
                o[dt] = __builtin_amdgcn_mfma_f32_16x16x32_bf16(vf, pf.v, o[dt], 0, 0, 0);
            }
        }
    }

    // single deferred l-reduction across the 4 grp groups
    float lrun = lpart;
    lrun += __shfl_xor(lrun, 16);
    lrun += __shfl_xor(lrun, 32);

    const float inv = (lrun > 0.f) ? 1.0f / lrun : 0.f;
    const size_t orow = ((size_t)batch * S + qt * 64 + wave * 16 + l15) * 64;
    #pragma unroll
    for (int dt = 0; dt < 4; ++dt) {
        f32x4 w = o[dt];
        w[0] *= inv; w[1] *= inv; w[2] *= inv; w[3] *= inv;
        *(f32x4*)(Out + orow + dt * 16 + grp * 4) = w;
    }
}

// ---------------- fallback (used only if ws too small) ----------------
__device__ __forceinline__ void load_tile_fb(const float* __restrict__ Kb,
                                             const float* __restrict__ Vb,
                                             int tid, f32x4 kv[4], f32x4 vv[4]) {
    #pragma unroll
    for (int h = 0; h < 4; ++h) {
        const int c = tid + h * 256;
        kv[h] = *(const f32x4*)(Kb + (c >> 4) * 64 + (c & 15) * 4);
    }
    #pragma unroll
    for (int h = 0; h < 2; ++h) {
        const int u  = tid + h * 256;
        const int d4 = (u & 3) + ((u >> 7) << 2);
        const int kp = (u >> 2) & 31;
        vv[2 * h]     = *(const f32x4*)(Vb + (2 * kp) * 64 + d4 * 4);
        vv[2 * h + 1] = *(const f32x4*)(Vb + (2 * kp + 1) * 64 + d4 * 4);
    }
}

__global__ __launch_bounds__(256, 4)
void attn_fb(const float* __restrict__ Qp, const float* __restrict__ Kp,
             const float* __restrict__ Vp, const int* __restrict__ meta,
             float* __restrict__ Out) {
    constexpr int S = SEQ;
    constexpr int qtiles = S >> 6;
    __shared__ short        lK [64 * KSTR];
    __shared__ unsigned int lVt[64 * VSTR];
    __shared__ unsigned int lPt[4 * 32 * PSTR];
    const int tid = threadIdx.x;
    const int wave = tid >> 6, lane = tid & 63;
    const int l15 = lane & 15, grp = lane >> 4;
    const int slot = blockIdx.x / qtiles, qt = blockIdx.x % qtiles;
    const int vl = meta[slot], batch = meta[BATCH + slot];
    const int ntiles = (vl + 63) >> 6;
    const float* Kb = Kp + (size_t)batch * S * 64;
    const float* Vb = Vp + (size_t)batch * S * 64;
    bf16x8 qf[2];
    {
        const float* qb = Qp + ((size_t)batch * S + qt * 64 + wave * 16 + l15) * 64 + grp * 8;
        #pragma unroll
        for (int kf = 0; kf < 2; ++kf) {
            f32x4 a = *(const f32x4*)(qb + kf * 32);
            f32x4 b = *(const f32x4*)(qb + kf * 32 + 4);
            union { bf16x8 v; unsigned int u[4]; } qq;
            qq.u[0] = pk2(a[0], a[1]); qq.u[1] = pk2(a[2], a[3]);
            qq.u[2] = pk2(b[0], b[1]); qq.u[3] = pk2(b[2], b[3]);
            qf[kf] = qq.v;
        }
    }
    f32x4 o[4] = {{0.f,0.f,0.f,0.f},{0.f,0.f,0.f,0.f},{0.f,0.f,0.f,0.f},{0.f,0.f,0.f,0.f}};
    float mrun = -INFINITY, lrun = 0.f;
    unsigned int* pw = &lPt[wave * 32 * PSTR];
    f32x4 kv[4], vv[4];
    if (ntiles > 0) load_tile_fb(Kb, Vb, tid, kv, vv);
    for (int kt = 0; kt < ntiles; ++kt) {
        const int kb = kt * 64;
        __syncthreads();
        #pragma unroll
        for (int h = 0; h < 4; ++h) {
            const int c = tid + h * 256;
            const int row = c >> 4, col = (c & 15) * 4;
            union { f32x4 f; float e[4]; } x; x.f = kv[h];
            unsigned int* dst = (unsigned int*)&lK[row * KSTR + col];
            dst[0] = pk2(x.e[0], x.e[1]); dst[1] = pk2(x.e[2], x.e[3]);
        }
        #pragma unroll
        for (int h = 0; h < 2; ++h) {
            const int u  = tid + h * 256;
            const int d4 = (u & 3) + ((u >> 7) << 2);
            const int kp = (u >> 2) & 31;
            union { f32x4 f; float e[4]; } a, b;
            a.f = vv[2 * h]; b.f = vv[2 * h + 1];
            #pragma unroll
            for (int j = 0; j < 4; ++j)
                lVt[(d4 * 4 + j) * VSTR + kp] = pk2(a.e[j], b.e[j]);
        }
        if (kt + 1 < ntiles) load_tile_fb(Kb + (size_t)(kb + 64) * 64, Vb + (size_t)(kb + 64) * 64, tid, kv, vv);
        __syncthreads();
        f32x4 st[4] = {{0.f,0.f,0.f,0.f},{0.f,0.f,0.f,0.f},{0.f,0.f,0.f,0.f},{0.f,0.f,0.f,0.f}};
        #pragma unroll
        for (int kf = 0; kf < 2; ++kf) {
            #pragma unroll
            for (int ct = 0; ct < 4; ++ct) {
                bf16x8 kfr = *(const bf16x8*)&lK[(ct * 16 + l15) * KSTR + kf * 32 + grp * 8];
                st[ct] = __builtin_amdgcn_mfma_f32_16x16x32_bf16(kfr, qf[kf], st[ct], 0, 0, 0);
            }
        }
        #pragma unroll
        for (int ct = 0; ct < 4; ++ct)
            #pragma unroll
            for (int r = 0; r < 4; ++r) {
                const bool valid = (kb + ct * 16 + grp * 4 + r) < vl;
                st[ct][r] = valid ? st[ct][r] * (0.125f * LOG2E) : NEGL;
            }
        float t0 = fmaxf(fmaxf(st[0][0], st[0][1]), fmaxf(st[0][2], st[0][3]));
        float t1 = fmaxf(fmaxf(st[1][0], st[1][1]), fmaxf(st[1][2], st[1][3]));
        float t2 = fmaxf(fmaxf(st[2][0], st[2][1]), fmaxf(st[2][2], st[2][3]));
        float t3 = fmaxf(fmaxf(st[3][0], st[3][1]), fmaxf(st[3][2], st[3][3]));
        float tm = fmaxf(fmaxf(t0, t1), fmaxf(t2, t3));
        tm = fmaxf(tm, __shfl_xor(tm, 16));
        tm = fmaxf(tm, __shfl_xor(tm, 32));
        const float mnew  = fmaxf(mrun, tm);
        const float alpha = exp2f(mrun - mnew);
        mrun = mnew;
        lrun *= alpha;
        #pragma unroll
        for (int dt = 0; dt < 4; ++dt)
            #pragma unroll
            for (int r = 0; r < 4; ++r) o[dt][r] *= alpha;
        float rs = 0.f;
        #pragma unroll
        for (int ct = 0; ct < 4; ++ct) {
            #pragma unroll
            for (int r = 0; r < 4; ++r) {
                st[ct][r] = exp2f(st[ct][r] - mrun);
                rs += st[ct][r];
            }
            #pragma unroll
            for (int a = 0; a < 2; ++a)
                pw[(ct * 8 + grp * 2 + a) * PSTR + l15] = pk2(st[ct][2 * a], st[ct][2 * a + 1]);
        }
        rs += __shfl_xor(rs, 16);
        rs += __shfl_xor(rs, 32);
        lrun += rs;
        asm volatile("s_waitcnt lgkmcnt(0)" ::: "memory");
        #pragma unroll
        for (int kk = 0; kk < 2; ++kk) {
            union { bf16x8 v; unsigned int u[4]; } pf;
            #pragma unroll
            for (int jj = 0; jj < 4; ++jj)
                pf.u[jj] = pw[(kk * 16 + grp * 4 + jj) * PSTR + l15];
            #pragma unroll
            for (int dt = 0; dt < 4; ++dt) {
                bf16x8 vf = *(const bf16x8*)&lVt[(dt * 16 + l15) * VSTR + kk * 16 + grp * 4];
                o[dt] = __builtin_amdgcn_mfma_f32_16x16x32_bf16(vf, pf.v, o[dt], 0, 0, 0);
            }
        }
    }
    const float inv = (lrun > 0.f) ? 1.0f / lrun : 0.f;
    const size_t orow = ((size_t)batch * S + qt * 64 + wave * 16 + l15) * 64;
    #pragma unroll
    for (int dt = 0; dt < 4; ++dt) {
        f32x4 w = o[dt];
        w[0] *= inv; w[1] *= inv; w[2] *= inv; w[3] *= inv;
        *(f32x4*)(Out + orow + dt * 16 + grp * 4) = w;
    }
}

extern "C" void kernel_launch(void* const* d_in, const int* in_sizes, int n_in,
                              void* d_out, int out_size, void* d_ws, size_t ws_size,
                              hipStream_t stream) {
    const float* Q  = (const float*)d_in[0];
    const float* K  = (const float*)d_in[1];
    const float* V  = (const float*)d_in[2];
    const int*   VL = (const int*)d_in[3];
    int* meta = (int*)d_ws;                    // 64 ints
    const size_t need = 512 + 2 * (size_t)BATCH * SEQ * 64 * sizeof(short);  // ~16.8 MB
    dim3 block(256);
    if (ws_size >= need) {
        short* Kb = (short*)((char*)d_ws + 512);
        short* Vt = Kb + (size_t)BATCH * SEQ * 64;
        prepkv<<<dim3(BATCH * 32 + 1), block, 0, stream>>>(K, V, VL, Kb, Vt, meta);
        attn_fwd<<<dim3(BATCH * 32), block, 0, stream>>>(Q, Kb, Vt, meta, (float*)d_out);
    } else {
        prep_vl<<<1, 64, 0, stream>>>(VL, meta);
        attn_fb<<<dim3(BATCH * (SEQ >> 6)), block, 0, stream>>>(Q, K, V, meta, (float*)d_out);
    }
}